// Round 5
// baseline (99.232 us; speedup 1.0000x reference)
//
#include <hip/hip_runtime.h>

// SoftFAPELoss: B=8, N=M=4096, D=3. Single-pass UNSHIFTED softmax.
// Math (unchanged from the 95.7us round): per-row shift sh = -c|p|^2 held in
// a register -> arg = sh - A = -c*d^2 <= 0, overflow impossible; chunk shift
// in d-units is exactly 0 so ALL partials merge with plain adds. Underflow
// safety: mx = max(arg) = -c*d^2_min tracked via v_max3 (0.5 slot/pair);
// finalize uses wd = -mx iff L == 0 (never on this data).
// This revision: occupancy-doubling reshape. BLOCK=256 (4 waves), ROWS=256
// (4 rows/lane), MSPL=16 (QCH=256, 64 q/wave), grid=2048 (8 blocks/CU).
// LDS 16 KB (was 56 KB) and __launch_bounds__(256,8) -> 8 waves/SIMD
// (was 4): 2x the TLP to hide exp2/ds_read/accum-chain latency behind the
// ~7.5-slot/pair issue floor. Per-lane work unchanged (256 pairs).
// Pg is chunk-major [ms][b*N+row] float4{L,S,mx,0} -> coalesced both sides.
// Finalize: plain streaming adds (all shifts are exactly 0), no exp2.

#define B_    8
#define N_    4096
#define M_    4096
#define NWAVE 4
#define BLOCK 256
#define ROWS  256                 // rows per block (4 per lane)
#define RPL   4                   // rows per lane
#define MSPL  16                  // M split across blocks
#define QCH   (M_ / MSPL)         // 256 q per block
#define WQ    (QCH / NWAVE)       // 64 q per wave
#define BN    (B_ * N_)           // 32768 rows
#define LOG2E 1.4426950408889634f
#define LN2   0.6931471805599453f
#define NEGBIG -3.0e38f

__global__ __launch_bounds__(BLOCK, 8) void softfape_main(
    const float* __restrict__ X_pred, const float* __restrict__ X_true,
    const float* __restrict__ R_pred, const float* __restrict__ t_pred,
    const float* __restrict__ R_true, const float* __restrict__ t_true,
    const float* __restrict__ temp,
    float4* __restrict__ Pg)
{
    __shared__ float4 Q[QCH];            // 4 KB
    __shared__ float  Lp[NWAVE][ROWS];   // 4 KB
    __shared__ float  Sp[NWAVE][ROWS];   // 4 KB
    __shared__ float  Mp[NWAVE][ROWS];   // 4 KB

    const int tid  = threadIdx.x;
    const int wave = tid >> 6;
    const int lane = tid & 63;
    const int x    = blockIdx.x;
    const int ms   = x & 15;             // M-chunk (16)
    const int rg   = (x >> 4) & 15;      // row group (256 rows each)
    const int b    = x >> 8;             // batch

    const float T   = temp[0];
    const float c   = LOG2E / T;
    const float m2c = -2.0f * c;

    // ---- stage 256 transformed+prescaled q's (1 per thread) ----
    // q.xyz = -2c*y, q.w = c*|y|^2  ->  A = q.p + q.w = c*(|y|^2 - 2 p.y)
    {
        const float g00 = R_true[b*9+0], g01 = R_true[b*9+1], g02 = R_true[b*9+2];
        const float g10 = R_true[b*9+3], g11 = R_true[b*9+4], g12 = R_true[b*9+5];
        const float g20 = R_true[b*9+6], g21 = R_true[b*9+7], g22 = R_true[b*9+8];
        const float u0  = t_true[b*3+0], u1 = t_true[b*3+1], u2 = t_true[b*3+2];
        const float* xt = X_true + ((size_t)b * M_ + ms * QCH + tid) * 3;
        const float rx = xt[0], ry = xt[1], rz = xt[2];
        const float y0 = fmaf(g00, rx, fmaf(g01, ry, fmaf(g02, rz, u0)));
        const float y1 = fmaf(g10, rx, fmaf(g11, ry, fmaf(g12, rz, u1)));
        const float y2 = fmaf(g20, rx, fmaf(g21, ry, fmaf(g22, rz, u2)));
        const float nn = fmaf(y0, y0, fmaf(y1, y1, y2 * y2));
        Q[tid] = make_float4(m2c*y0, m2c*y1, m2c*y2, c*nn);
    }

    // ---- my 4 rows: transformed pred points; sh[r] = -c*|p|^2 (register) ----
    float px[RPL], py[RPL], pz[RPL], sh[RPL];
    {
        const float h00 = R_pred[b*9+0], h01 = R_pred[b*9+1], h02 = R_pred[b*9+2];
        const float h10 = R_pred[b*9+3], h11 = R_pred[b*9+4], h12 = R_pred[b*9+5];
        const float h20 = R_pred[b*9+6], h21 = R_pred[b*9+7], h22 = R_pred[b*9+8];
        const float v0 = t_pred[b*3+0], v1 = t_pred[b*3+1], v2 = t_pred[b*3+2];
        const float4* xp = (const float4*)(X_pred + ((size_t)b * N_ + rg * ROWS + lane * RPL) * 3);
        const float4 a0 = xp[0], a1 = xp[1], a2 = xp[2];   // 12 floats = 4 rows
        const float rx[4] = {a0.x, a0.w, a1.z, a2.y};
        const float ry[4] = {a0.y, a1.x, a1.w, a2.z};
        const float rz[4] = {a0.z, a1.y, a2.x, a2.w};
        #pragma unroll
        for (int r = 0; r < RPL; ++r) {
            px[r] = fmaf(h00, rx[r], fmaf(h01, ry[r], fmaf(h02, rz[r], v0)));
            py[r] = fmaf(h10, rx[r], fmaf(h11, ry[r], fmaf(h12, rz[r], v1)));
            pz[r] = fmaf(h20, rx[r], fmaf(h21, ry[r], fmaf(h22, rz[r], v2)));
            sh[r] = -c * fmaf(px[r], px[r], fmaf(py[r], py[r], pz[r] * pz[r]));
        }
    }

    __syncthreads();   // Q ready

    const float4* __restrict__ Qw = Q + wave * WQ;

    // ---- single pass over my 64-q slice: arg = sh - A = -c*d^2 <= 0 ----
    float L[RPL], S[RPL], mx[RPL];
    #pragma unroll
    for (int r = 0; r < RPL; ++r) { L[r] = 0.0f; S[r] = 0.0f; mx[r] = NEGBIG; }
    for (int k0 = 0; k0 < WQ; k0 += 4) {
        float4 qv[4];
        #pragma unroll
        for (int j = 0; j < 4; ++j) qv[j] = Qw[k0 + j];   // wave-uniform broadcast
        #pragma unroll
        for (int j2 = 0; j2 < 2; ++j2) {
            const float4 q0 = qv[2*j2], q1 = qv[2*j2+1];
            #pragma unroll
            for (int r = 0; r < RPL; ++r) {
                const float A0   = fmaf(q0.x, px[r], fmaf(q0.y, py[r], fmaf(q0.z, pz[r], q0.w)));
                const float A1   = fmaf(q1.x, px[r], fmaf(q1.y, py[r], fmaf(q1.z, pz[r], q1.w)));
                const float arg0 = sh[r] - A0;
                const float arg1 = sh[r] - A1;
                const float w0   = __builtin_amdgcn_exp2f(arg0);
                const float w1   = __builtin_amdgcn_exp2f(arg1);
                L[r] += w0;
                L[r] += w1;
                S[r]  = fmaf(w0, arg0, S[r]);
                S[r]  = fmaf(w1, arg1, S[r]);
                mx[r] = fmaxf(fmaxf(mx[r], arg0), arg1);   // -> v_max3_f32
            }
        }
    }
    *(float4*)&Lp[wave][RPL*lane] = make_float4(L[0], L[1], L[2], L[3]);
    *(float4*)&Sp[wave][RPL*lane] = make_float4(S[0], S[1], S[2], S[3]);
    *(float4*)&Mp[wave][RPL*lane] = make_float4(mx[0], mx[1], mx[2], mx[3]);
    __syncthreads();

    // ---- merge 4 wave-partials per row (shift 0 -> plain adds) ----
    {
        float Lr = Lp[0][tid], Sr = Sp[0][tid], mw = Mp[0][tid];
        #pragma unroll
        for (int w2 = 1; w2 < NWAVE; ++w2) {
            Lr += Lp[w2][tid];
            Sr += Sp[w2][tid];
            mw  = fmaxf(mw, Mp[w2][tid]);
        }
        const size_t row = (size_t)b * N_ + rg * ROWS + tid;
        // chunk-major layout: coalesced write here, coalesced read in finalize
        Pg[(size_t)ms * BN + row] = make_float4(Lr, Sr, mw, 0.0f);
    }
}

__global__ __launch_bounds__(256) void softfape_finalize(
    const float4* __restrict__ Pg, const float* __restrict__ temp,
    float* __restrict__ out)
{
    __shared__ float ws4[4];
    const int tid = threadIdx.x;
    const size_t row = (size_t)blockIdx.x * 256 + tid;

    // all chunk shifts are exactly 0.0f -> merge is plain streaming adds
    float L = 0.0f, SA = 0.0f, mw = NEGBIG;
    #pragma unroll
    for (int i = 0; i < MSPL; ++i) {
        const float4 P = Pg[(size_t)i * BN + row];
        L  += P.x;
        SA += P.y;
        mw  = fmaxf(mw, P.z);
    }
    // wd = c * weighted_distance(row). If every weight flushed to zero
    // (c*d^2_min > ~126, never on this data), softmax ~= argmin: wd = -mw.
    const float wd0 = (L > 0.0f) ? (-SA / L) : -mw;
    float wd = wd0;

    wd += __shfl_xor(wd, 1);  wd += __shfl_xor(wd, 2);  wd += __shfl_xor(wd, 4);
    wd += __shfl_xor(wd, 8);  wd += __shfl_xor(wd, 16); wd += __shfl_xor(wd, 32);
    if ((tid & 63) == 0) ws4[tid >> 6] = wd;
    __syncthreads();
    if (tid == 0) {
        const float s = ws4[0] + ws4[1] + ws4[2] + ws4[3];
        const float scale = temp[0] * LN2 / ((float)B_ * (float)N_);  // 1/c, mean
        atomicAdd(out, s * scale);
    }
}

extern "C" void kernel_launch(void* const* d_in, const int* in_sizes, int n_in,
                              void* d_out, int out_size, void* d_ws, size_t ws_size,
                              hipStream_t stream) {
    const float* X_pred = (const float*)d_in[0];
    const float* X_true = (const float*)d_in[1];
    const float* R_pred = (const float*)d_in[2];
    const float* t_pred = (const float*)d_in[3];
    const float* R_true = (const float*)d_in[4];
    const float* t_true = (const float*)d_in[5];
    const float* temp   = (const float*)d_in[6];
    float* out = (float*)d_out;

    float4* Pg = (float4*)d_ws;   // MSPL * B*N float4 = 8 MB, fully overwritten

    hipMemsetAsync(out, 0, sizeof(float), stream);

    // 2048 blocks: b(8) x rowgroup(16) x mchunk(16); 4 waves, 4 rows/lane
    softfape_main<<<dim3(B_ * (N_ / ROWS) * MSPL), BLOCK, 0, stream>>>(
        X_pred, X_true, R_pred, t_pred, R_true, t_true, temp, Pg);

    softfape_finalize<<<dim3(BN / 256), 256, 0, stream>>>(Pg, temp, out);
}

// Round 7
// 92.745 us; speedup vs baseline: 1.0700x; 1.0700x over previous
//
#include <hip/hip_runtime.h>

// SoftFAPELoss: B=8, N=M=4096, D=3. Single-pass UNSHIFTED softmax.
// (Round-4 winning structure; cooperative fusion failed: hipLaunchCooperative-
// Kernel is not graph-capturable in this harness -> launch silently dropped.)
//
// Math: per-row shift sh = -c|p|^2 held in a register -> arg = sh - A =
// -c*d^2 <= 0: overflow impossible. Chunk shift in d-units is exactly 0, so
// all partials merge with plain adds (power-of-2 shifts are exact in f32).
// Underflow safety: mx = max(arg) = -c*d^2_min per row (v_max3, 0.5
// slot/pair); finalize uses wd = -mx iff L == 0 (never fires on this data).
// Q staged prescaled: q.xyz = -2c*y, q.w = c*|y|^2 -> A = q.p + q.w.
// Inner loop per pair: 3 fma + sub + exp2 + add + fma + 0.5 max3;
// 8 rows/lane amortize each wave-uniform ds_read_b128.
//
// Dispatch-count reduction (graph-safe): out is zeroed by one thread of
// softfape_main (stream ordering makes it visible before finalize's
// atomicAdds) -> the hipMemsetAsync dispatch is deleted. 3 dispatches/iter
// incl. harness ws-fill. Pg is chunk-major [ms][b*N+row] {L,S,mx,0}:
// coalesced write in main, coalesced loads in finalize, L2-resident.

#define B_    8
#define N_    4096
#define M_    4096
#define NWAVE 8
#define BLOCK 512
#define ROWS  512                 // rows per block (8 per lane)
#define RPL   8                   // rows per lane
#define MSPL  8                   // M split across blocks
#define QCH   (M_ / MSPL)         // 512 q per block
#define WQ    (QCH / NWAVE)       // 64 q per wave
#define BN    (B_ * N_)           // 32768 rows
#define LOG2E 1.4426950408889634f
#define LN2   0.6931471805599453f
#define NEGBIG -3.0e38f

__global__ __launch_bounds__(BLOCK, 4) void softfape_main(
    const float* __restrict__ X_pred, const float* __restrict__ X_true,
    const float* __restrict__ R_pred, const float* __restrict__ t_pred,
    const float* __restrict__ R_true, const float* __restrict__ t_true,
    const float* __restrict__ temp,
    float4* __restrict__ Pg, float* __restrict__ out)
{
    __shared__ float4 Q[QCH];            //  8 KB
    __shared__ float  Lp[NWAVE][ROWS];   // 16 KB
    __shared__ float  Sp[NWAVE][ROWS];   // 16 KB
    __shared__ float  Mp[NWAVE][ROWS];   // 16 KB

    const int tid  = threadIdx.x;
    const int wave = tid >> 6;
    const int lane = tid & 63;
    const int x    = blockIdx.x;
    const int ms   = x & 7;              // M-chunk
    const int rg   = (x >> 3) & 7;       // row group (512 rows)
    const int b    = x >> 6;             // batch

    const float T   = temp[0];
    const float c   = LOG2E / T;
    const float m2c = -2.0f * c;

    // replaces the memsetAsync dispatch; stream order makes this visible
    // to softfape_finalize's atomicAdds
    if (x == 0 && tid == 0) out[0] = 0.0f;

    // ---- stage 512 transformed+prescaled q's (1 per thread) ----
    // q.xyz = -2c*y, q.w = c*|y|^2  ->  A = q.p + q.w = c*(|y|^2 - 2 p.y)
    {
        const float g00 = R_true[b*9+0], g01 = R_true[b*9+1], g02 = R_true[b*9+2];
        const float g10 = R_true[b*9+3], g11 = R_true[b*9+4], g12 = R_true[b*9+5];
        const float g20 = R_true[b*9+6], g21 = R_true[b*9+7], g22 = R_true[b*9+8];
        const float u0  = t_true[b*3+0], u1 = t_true[b*3+1], u2 = t_true[b*3+2];
        const float* xt = X_true + ((size_t)b * M_ + ms * QCH + tid) * 3;
        const float rx = xt[0], ry = xt[1], rz = xt[2];
        const float y0 = fmaf(g00, rx, fmaf(g01, ry, fmaf(g02, rz, u0)));
        const float y1 = fmaf(g10, rx, fmaf(g11, ry, fmaf(g12, rz, u1)));
        const float y2 = fmaf(g20, rx, fmaf(g21, ry, fmaf(g22, rz, u2)));
        const float nn = fmaf(y0, y0, fmaf(y1, y1, y2 * y2));
        Q[tid] = make_float4(m2c*y0, m2c*y1, m2c*y2, c*nn);
    }

    // ---- my 8 rows: transformed pred points; sh[r] = -c*|p|^2 (register) ----
    float px[RPL], py[RPL], pz[RPL], sh[RPL];
    {
        const float h00 = R_pred[b*9+0], h01 = R_pred[b*9+1], h02 = R_pred[b*9+2];
        const float h10 = R_pred[b*9+3], h11 = R_pred[b*9+4], h12 = R_pred[b*9+5];
        const float h20 = R_pred[b*9+6], h21 = R_pred[b*9+7], h22 = R_pred[b*9+8];
        const float v0 = t_pred[b*3+0], v1 = t_pred[b*3+1], v2 = t_pred[b*3+2];
        const float4* xp = (const float4*)(X_pred + ((size_t)b * N_ + rg * ROWS + lane * RPL) * 3);
        float f[24];
        #pragma unroll
        for (int i = 0; i < 6; ++i) *(float4*)&f[4*i] = xp[i];
        #pragma unroll
        for (int r = 0; r < RPL; ++r) {
            const float rx = f[3*r], ry = f[3*r+1], rz = f[3*r+2];
            px[r] = fmaf(h00, rx, fmaf(h01, ry, fmaf(h02, rz, v0)));
            py[r] = fmaf(h10, rx, fmaf(h11, ry, fmaf(h12, rz, v1)));
            pz[r] = fmaf(h20, rx, fmaf(h21, ry, fmaf(h22, rz, v2)));
            sh[r] = -c * fmaf(px[r], px[r], fmaf(py[r], py[r], pz[r] * pz[r]));
        }
    }

    __syncthreads();   // Q ready

    const float4* __restrict__ Qw = Q + wave * WQ;

    // ---- single pass over my 64-q slice: arg = sh - A = -c*d^2 <= 0 ----
    float L[RPL], S[RPL], mx[RPL];
    #pragma unroll
    for (int r = 0; r < RPL; ++r) { L[r] = 0.0f; S[r] = 0.0f; mx[r] = NEGBIG; }
    for (int k0 = 0; k0 < WQ; k0 += 8) {
        float4 qv[8];
        #pragma unroll
        for (int j = 0; j < 8; ++j) qv[j] = Qw[k0 + j];   // wave-uniform broadcast
        #pragma unroll
        for (int j2 = 0; j2 < 4; ++j2) {
            const float4 q0 = qv[2*j2], q1 = qv[2*j2+1];
            #pragma unroll
            for (int r = 0; r < RPL; ++r) {
                const float A0   = fmaf(q0.x, px[r], fmaf(q0.y, py[r], fmaf(q0.z, pz[r], q0.w)));
                const float A1   = fmaf(q1.x, px[r], fmaf(q1.y, py[r], fmaf(q1.z, pz[r], q1.w)));
                const float arg0 = sh[r] - A0;
                const float arg1 = sh[r] - A1;
                const float w0   = __builtin_amdgcn_exp2f(arg0);
                const float w1   = __builtin_amdgcn_exp2f(arg1);
                L[r] += w0;
                L[r] += w1;
                S[r]  = fmaf(w0, arg0, S[r]);
                S[r]  = fmaf(w1, arg1, S[r]);
                mx[r] = fmaxf(fmaxf(mx[r], arg0), arg1);   // -> v_max3_f32
            }
        }
    }
    *(float4*)&Lp[wave][RPL*lane]     = make_float4(L[0], L[1], L[2], L[3]);
    *(float4*)&Lp[wave][RPL*lane + 4] = make_float4(L[4], L[5], L[6], L[7]);
    *(float4*)&Sp[wave][RPL*lane]     = make_float4(S[0], S[1], S[2], S[3]);
    *(float4*)&Sp[wave][RPL*lane + 4] = make_float4(S[4], S[5], S[6], S[7]);
    *(float4*)&Mp[wave][RPL*lane]     = make_float4(mx[0], mx[1], mx[2], mx[3]);
    *(float4*)&Mp[wave][RPL*lane + 4] = make_float4(mx[4], mx[5], mx[6], mx[7]);
    __syncthreads();

    // ---- merge 8 wave-partials per row (shift 0 -> plain adds) ----
    {
        float Lr = Lp[0][tid], Sr = Sp[0][tid], mw = Mp[0][tid];
        #pragma unroll
        for (int w2 = 1; w2 < NWAVE; ++w2) {
            Lr += Lp[w2][tid];
            Sr += Sp[w2][tid];
            mw  = fmaxf(mw, Mp[w2][tid]);
        }
        const size_t row = (size_t)b * N_ + rg * ROWS + tid;
        Pg[(size_t)ms * BN + row] = make_float4(Lr, Sr, mw, 0.0f);   // chunk-major
    }
}

__global__ __launch_bounds__(256) void softfape_finalize(
    const float4* __restrict__ Pg, const float* __restrict__ temp,
    float* __restrict__ out)
{
    __shared__ float ws4[4];
    const int tid = threadIdx.x;
    const size_t row = (size_t)blockIdx.x * 256 + tid;

    // all chunk shifts are exactly 0.0f -> merge is plain streaming adds
    float L = 0.0f, SA = 0.0f, mw = NEGBIG;
    #pragma unroll
    for (int i = 0; i < MSPL; ++i) {
        const float4 P = Pg[(size_t)i * BN + row];   // coalesced across lanes
        L  += P.x;
        SA += P.y;
        mw  = fmaxf(mw, P.z);
    }
    // wd = c * weighted_distance(row). If every weight flushed to zero
    // (c*d^2_min > ~126, never on this data), softmax ~= argmin: wd = -mw.
    float wd = (L > 0.0f) ? (-SA / L) : -mw;

    wd += __shfl_xor(wd, 1);  wd += __shfl_xor(wd, 2);  wd += __shfl_xor(wd, 4);
    wd += __shfl_xor(wd, 8);  wd += __shfl_xor(wd, 16); wd += __shfl_xor(wd, 32);
    if ((tid & 63) == 0) ws4[tid >> 6] = wd;
    __syncthreads();
    if (tid == 0) {
        const float s = ws4[0] + ws4[1] + ws4[2] + ws4[3];
        const float scale = temp[0] * LN2 / ((float)B_ * (float)N_);  // 1/c, mean
        atomicAdd(out, s * scale);
    }
}

extern "C" void kernel_launch(void* const* d_in, const int* in_sizes, int n_in,
                              void* d_out, int out_size, void* d_ws, size_t ws_size,
                              hipStream_t stream) {
    const float* X_pred = (const float*)d_in[0];
    const float* X_true = (const float*)d_in[1];
    const float* R_pred = (const float*)d_in[2];
    const float* t_pred = (const float*)d_in[3];
    const float* R_true = (const float*)d_in[4];
    const float* t_true = (const float*)d_in[5];
    const float* temp   = (const float*)d_in[6];
    float* out = (float*)d_out;

    float4* Pg = (float4*)d_ws;   // MSPL * B*N float4 = 4 MB, fully overwritten

    // 512 blocks: b(8) x rowgroup(8) x mchunk(8); 8 waves, 8 rows/lane.
    // out is zeroed inside softfape_main (no memset dispatch).
    softfape_main<<<dim3(B_ * (N_ / ROWS) * MSPL), BLOCK, 0, stream>>>(
        X_pred, X_true, R_pred, t_pred, R_true, t_true, temp, Pg, out);

    softfape_finalize<<<dim3(BN / 256), 256, 0, stream>>>(Pg, temp, out);
}